// Round 4
// baseline (301.800 us; speedup 1.0000x reference)
//
#include <hip/hip_runtime.h>
#include <hip/hip_bf16.h>

// FraudDetectionHybrid: h1=tanh(x@W1^T+b1); h2=tanh(h1@W2^T+b2);
// sq_ij=|h2_i|^2+|h2_j|^2-2*h2_i.h2_j; out=exp(-g*sq)@Wc^T+bc
// GEMM1/2: 256x256 quadrant-phase bf16 MFMA, ASM barriers (no compiler
// vmcnt(0) drain), one counted vmcnt(8) per K-tile. Gram: triangular 128^2.

#define NROWS 4096
#define HID   4096
#define INDIM 512
#define GAMMA_F 5e-4f

typedef float f32x4 __attribute__((ext_vector_type(4)));
typedef short bf16x8 __attribute__((ext_vector_type(8)));

#define BAR() asm volatile("s_barrier" ::: "memory")

__device__ __forceinline__ unsigned short f2bf_rne(float f) {
  union { float f; unsigned int u; } v; v.f = f;
  unsigned int r = v.u + 0x7FFFu + ((v.u >> 16) & 1u);
  return (unsigned short)(r >> 16);
}
__device__ __forceinline__ float bf2f(unsigned short u) {
  union { unsigned int u; float f; } v; v.u = ((unsigned int)u) << 16; return v.f;
}

__global__ void cast_f32_bf16(const float* __restrict__ src,
                              unsigned short* __restrict__ dst, int n4) {
  int i = blockIdx.x * blockDim.x + threadIdx.x;
  if (i >= n4) return;
  float4 v = ((const float4*)src)[i];
  ushort4 o;
  o.x = f2bf_rne(v.x); o.y = f2bf_rne(v.y);
  o.z = f2bf_rne(v.z); o.w = f2bf_rne(v.w);
  ((ushort4*)dst)[i] = o;
}

__global__ void init_vecs(float* __restrict__ out, float* __restrict__ norms,
                          const float* __restrict__ bc, int n) {
  int i = blockIdx.x * blockDim.x + threadIdx.x;
  if (i < n) { out[i] = bc[0]; norms[i] = 0.f; }
}

__device__ __forceinline__ void gload16(const void* g, void* l) {
  __builtin_amdgcn_global_load_lds(
      (const __attribute__((address_space(1))) void*)g,
      (__attribute__((address_space(3))) void*)l, 16, 0, 0);
}

// ---------------------------------------------------------------------------
// 256x256 NT GEMM, BK=64, 8 waves (2Mx4N). 4 quadrant-phases per K-tile:
//   ph1: read A[mi0-3]x2kh + B[nj0-1]x2kh (12) | MFMA Q(mi0-3,nj0-1) x K64
//   ph2: read B[nj2-3]x2kh (4)                 | MFMA Q(mi0-3,nj2-3)
//   ph3: read A[mi4-7]x2kh (8) | stage B(t+2)  | MFMA Q(mi4-7,nj0-1)
//   ph4: stage A(t+2) | MFMA Q(mi4-7,nj2-3) | vmcnt(8) | barrier
// All barriers are inline-asm s_barrier (compiler cannot insert a vmcnt(0)
// drain in front). lgkmcnt(0) before trailing barriers of ph2/ph3 gives the
// strict reads-complete-before-overwrite guarantee for the t+2 stages.
// EPI 0: Hout = bf16(tanh(acc+bias)); EPI 2: + fused row-norm atomics.
// ---------------------------------------------------------------------------
template <int EPI>
__global__ __launch_bounds__(512, 2)
void gemm256(const unsigned short* __restrict__ A, const unsigned short* __restrict__ B,
             int K, int N,
             const float* __restrict__ bias, unsigned short* __restrict__ Hout,
             float* __restrict__ norms_out) {
  __shared__ __align__(16) unsigned short As[2][2][256 * 32];
  __shared__ __align__(16) unsigned short Bs[2][2][256 * 32];

  const int tid  = threadIdx.x;
  const int lane = tid & 63;
  const int wave = tid >> 6;
  const int wr = wave >> 2, wc = wave & 3;   // 2x4 wave grid, 128x64 out each
  const int fr = lane & 15, fq = lane >> 4;

  const int nwg = gridDim.x;
  const int cpx = nwg >> 3;
  const int bid = blockIdx.x;
  const int swz = (bid & 7) * cpx + (bid >> 3);
  const int nbx = N >> 8;
  const int brow = (swz / nbx) << 8;
  const int bcol = (swz % nbx) << 8;

  const int i0 = tid, i1 = 512 + tid;
  const int r0 = i0 >> 2, r1 = i1 >> 2;
  const int sc0 = ((i0 & 3) ^ ((r0 >> 1) & 3)) << 3;
  const int sc1 = ((i1 & 3) ^ ((r1 >> 1) & 3)) << 3;
  const int ld0 = (wave * 64) * 8;
  const int ld1 = (512 + wave * 64) * 8;
  const unsigned short* a0 = A + (size_t)(brow + r0) * K + sc0;
  const unsigned short* a1 = A + (size_t)(brow + r1) * K + sc1;
  const unsigned short* b0 = B + (size_t)(bcol + r0) * K + sc0;
  const unsigned short* b1 = B + (size_t)(bcol + r1) * K + sc1;

#define STAGE_A(p, kh, tt) do { int kk = (tt) * 64 + (kh) * 32;  \
    gload16(a0 + kk, &As[p][kh][ld0]);                           \
    gload16(a1 + kk, &As[p][kh][ld1]); } while (0)
#define STAGE_B(p, kh, tt) do { int kk = (tt) * 64 + (kh) * 32;  \
    gload16(b0 + kk, &Bs[p][kh][ld0]);                           \
    gload16(b1 + kk, &Bs[p][kh][ld1]); } while (0)

  int aoff[8], boff[4];
#pragma unroll
  for (int mi = 0; mi < 8; ++mi) {
    int row = wr * 128 + mi * 16 + fr;
    aoff[mi] = row * 32 + ((fq ^ ((row >> 1) & 3)) << 3);
  }
#pragma unroll
  for (int nj = 0; nj < 4; ++nj) {
    int row = wc * 64 + nj * 16 + fr;
    boff[nj] = row * 32 + ((fq ^ ((row >> 1) & 3)) << 3);
  }

  const int NT = K >> 6;

  // prologue: tiles 0 and 1 fully staged (16 loads/thread)
  STAGE_A(0, 0, 0); STAGE_A(0, 1, 0); STAGE_B(0, 0, 0); STAGE_B(0, 1, 0);
  STAGE_A(1, 0, 1); STAGE_A(1, 1, 1); STAGE_B(1, 0, 1); STAGE_B(1, 1, 1);
  asm volatile("s_waitcnt vmcnt(8)" ::: "memory");  // tile0's 8 landed
  BAR();

  f32x4 acc[8][4] = {};
  bf16x8 afr[8], bf01[4], bf23[4];

  for (int t = 0; t < NT; ++t) {
    const int p = t & 1;
    int t2 = t + 2; if (t2 >= NT) t2 -= NT;  // wrapped dummy stage at tail

    // ---- ph1: A[mi0-3] + B[nj0-1], both kh (12 reads) ----
#pragma unroll
    for (int kh = 0; kh < 2; ++kh)
#pragma unroll
      for (int mi = 0; mi < 4; ++mi)
        afr[kh * 4 + mi] = *(const bf16x8*)&As[p][kh][aoff[mi]];
#pragma unroll
    for (int kh = 0; kh < 2; ++kh)
#pragma unroll
      for (int nj = 0; nj < 2; ++nj)
        bf01[kh * 2 + nj] = *(const bf16x8*)&Bs[p][kh][boff[nj]];
    BAR();
    __builtin_amdgcn_s_setprio(1);
#pragma unroll
    for (int kh = 0; kh < 2; ++kh)
#pragma unroll
      for (int mi = 0; mi < 4; ++mi)
#pragma unroll
        for (int nj = 0; nj < 2; ++nj)
          acc[mi][nj] = __builtin_amdgcn_mfma_f32_16x16x32_bf16(
              afr[kh * 4 + mi], bf01[kh * 2 + nj], acc[mi][nj], 0, 0, 0);
    __builtin_amdgcn_s_setprio(0);
    BAR();

    // ---- ph2: B[nj2-3] (4 reads) ----
#pragma unroll
    for (int kh = 0; kh < 2; ++kh)
#pragma unroll
      for (int nj = 0; nj < 2; ++nj)
        bf23[kh * 2 + nj] = *(const bf16x8*)&Bs[p][kh][boff[2 + nj]];
    BAR();
    __builtin_amdgcn_s_setprio(1);
#pragma unroll
    for (int kh = 0; kh < 2; ++kh)
#pragma unroll
      for (int mi = 0; mi < 4; ++mi)
#pragma unroll
        for (int nj = 0; nj < 2; ++nj)
          acc[mi][2 + nj] = __builtin_amdgcn_mfma_f32_16x16x32_bf16(
              afr[kh * 4 + mi], bf23[kh * 2 + nj], acc[mi][2 + nj], 0, 0, 0);
    __builtin_amdgcn_s_setprio(0);
    asm volatile("s_waitcnt lgkmcnt(0)" ::: "memory");  // all B-reads done -> ph3 may overwrite Bs[p]
    BAR();

    // ---- ph3: A[mi4-7] (8 reads, reuse afr bank); stage B(t+2) ----
#pragma unroll
    for (int kh = 0; kh < 2; ++kh)
#pragma unroll
      for (int mi = 0; mi < 4; ++mi)
        afr[kh * 4 + mi] = *(const bf16x8*)&As[p][kh][aoff[4 + mi]];
    STAGE_B(p, 0, t2); STAGE_B(p, 1, t2);
    BAR();
    __builtin_amdgcn_s_setprio(1);
#pragma unroll
    for (int kh = 0; kh < 2; ++kh)
#pragma unroll
      for (int mi = 0; mi < 4; ++mi)
#pragma unroll
        for (int nj = 0; nj < 2; ++nj)
          acc[4 + mi][nj] = __builtin_amdgcn_mfma_f32_16x16x32_bf16(
              afr[kh * 4 + mi], bf01[kh * 2 + nj], acc[4 + mi][nj], 0, 0, 0);
    __builtin_amdgcn_s_setprio(0);
    asm volatile("s_waitcnt lgkmcnt(0)" ::: "memory");  // all A-reads done -> ph4 may overwrite As[p]
    BAR();

    // ---- ph4: no reads; stage A(t+2); counted vmcnt ----
    STAGE_A(p, 0, t2); STAGE_A(p, 1, t2);
    __builtin_amdgcn_s_setprio(1);
#pragma unroll
    for (int kh = 0; kh < 2; ++kh)
#pragma unroll
      for (int mi = 0; mi < 4; ++mi)
#pragma unroll
        for (int nj = 0; nj < 2; ++nj)
          acc[4 + mi][2 + nj] = __builtin_amdgcn_mfma_f32_16x16x32_bf16(
              afr[kh * 4 + mi], bf23[kh * 2 + nj], acc[4 + mi][2 + nj], 0, 0, 0);
    __builtin_amdgcn_s_setprio(0);
    asm volatile("s_waitcnt vmcnt(8)" ::: "memory");  // t+1's tile fully landed
    BAR();
  }
  asm volatile("s_waitcnt vmcnt(0)" ::: "memory");

  // C/D layout: col = lane&15, row = (lane>>4)*4 + reg
  float bv[4];
#pragma unroll
  for (int nj = 0; nj < 4; ++nj) bv[nj] = bias[bcol + wc * 64 + nj * 16 + fr];
#pragma unroll
  for (int mi = 0; mi < 8; ++mi) {
    int row0 = brow + wr * 128 + mi * 16 + fq * 4;
#pragma unroll
    for (int rr = 0; rr < 4; ++rr) {
      float ns = 0.f;
#pragma unroll
      for (int nj = 0; nj < 4; ++nj) {
        float v = tanhf(acc[mi][nj][rr] + bv[nj]);
        Hout[(size_t)(row0 + rr) * N + (bcol + wc * 64 + nj * 16 + fr)] = f2bf_rne(v);
        if (EPI == 2) ns += v * v;
      }
      if (EPI == 2) {
        ns += __shfl_xor(ns, 1);
        ns += __shfl_xor(ns, 2);
        ns += __shfl_xor(ns, 4);
        ns += __shfl_xor(ns, 8);
        if (fr == 0) atomicAdd(&norms_out[row0 + rr], ns);
      }
    }
  }
#undef STAGE_A
#undef STAGE_B
}

// ---------------------------------------------------------------------------
// Triangular gram: 128x128 tiles over the lower triangle (528 blocks).
// ---------------------------------------------------------------------------
__global__ __launch_bounds__(256, 2)
void gram_tri(const unsigned short* __restrict__ H, int K,
              const float* __restrict__ norms, const float* __restrict__ Wc,
              float* __restrict__ out) {
  __shared__ __align__(16) unsigned short As[128 * 32];
  __shared__ __align__(16) unsigned short Bs[128 * 32];

  const int tid  = threadIdx.x;
  const int lane = tid & 63;
  const int wave = tid >> 6;
  const int wr = wave >> 1, wc = wave & 1;
  const int fr = lane & 15, fq = lane >> 4;

  const int bid = blockIdx.x;
  const int swz = (bid & 7) * 66 + (bid >> 3);
  int I = (int)((sqrtf(8.0f * (float)swz + 1.0f) - 1.0f) * 0.5f);
  while ((I + 1) * (I + 2) / 2 <= swz) ++I;
  while (I * (I + 1) / 2 > swz) --I;
  const int J = swz - I * (I + 1) / 2;
  const int brow = I << 7, bcol = J << 7;
  const bool diag = (I == J);

  f32x4 acc[4][4] = {};

  for (int k0 = 0; k0 < K; k0 += 32) {
    __syncthreads();
#pragma unroll
    for (int q = 0; q < 2; ++q) {
      int idx = q * 256 + tid;
      int row = idx >> 2, c = idx & 3;
      int col = (c ^ ((row >> 1) & 3)) << 3;
      gload16(H + (size_t)(brow + row) * K + k0 + col, &As[(q * 256 + wave * 64) * 8]);
      gload16(H + (size_t)(bcol + row) * K + k0 + col, &Bs[(q * 256 + wave * 64) * 8]);
    }
    __syncthreads();

    bf16x8 af[4], bfrag[4];
#pragma unroll
    for (int mi = 0; mi < 4; ++mi) {
      int row = wr * 64 + mi * 16 + fr;
      af[mi] = *(const bf16x8*)&As[row * 32 + ((fq ^ ((row >> 1) & 3)) << 3)];
    }
#pragma unroll
    for (int nj = 0; nj < 4; ++nj) {
      int row = wc * 64 + nj * 16 + fr;
      bfrag[nj] = *(const bf16x8*)&Bs[row * 32 + ((fq ^ ((row >> 1) & 3)) << 3)];
    }
#pragma unroll
    for (int mi = 0; mi < 4; ++mi)
#pragma unroll
      for (int nj = 0; nj < 4; ++nj)
        acc[mi][nj] = __builtin_amdgcn_mfma_f32_16x16x32_bf16(af[mi], bfrag[nj], acc[mi][nj], 0, 0, 0);
  }

  float ncol[4], wcv[4];
#pragma unroll
  for (int nj = 0; nj < 4; ++nj) {
    int col = bcol + wc * 64 + nj * 16 + fr;
    ncol[nj] = norms[col];
    wcv[nj]  = Wc[col];
  }
  float colpart[4] = {0.f, 0.f, 0.f, 0.f};
#pragma unroll
  for (int mi = 0; mi < 4; ++mi) {
    int row0 = brow + wr * 64 + mi * 16 + fq * 4;
    float4 nr4  = *(const float4*)&norms[row0];
    float4 wcr4 = *(const float4*)&Wc[row0];
#pragma unroll
    for (int rr = 0; rr < 4; ++rr) {
      float nrow = (rr == 0) ? nr4.x : (rr == 1) ? nr4.y : (rr == 2) ? nr4.z : nr4.w;
      float wrow = (rr == 0) ? wcr4.x : (rr == 1) ? wcr4.y : (rr == 2) ? wcr4.z : wcr4.w;
      float rowpart = 0.f;
#pragma unroll
      for (int nj = 0; nj < 4; ++nj) {
        float sq = nrow + ncol[nj] - 2.0f * acc[mi][nj][rr];
        float e = __expf(-GAMMA_F * sq);
        rowpart += e * wcv[nj];
        colpart[nj] += e * wrow;
      }
      rowpart += __shfl_xor(rowpart, 1);
      rowpart += __shfl_xor(rowpart, 2);
      rowpart += __shfl_xor(rowpart, 4);
      rowpart += __shfl_xor(rowpart, 8);
      if (fr == 0) atomicAdd(&out[row0 + rr], rowpart);
    }
  }
  if (!diag) {
#pragma unroll
    for (int nj = 0; nj < 4; ++nj) {
      colpart[nj] += __shfl_xor(colpart[nj], 16);
      colpart[nj] += __shfl_xor(colpart[nj], 32);
      if (fq == 0) atomicAdd(&out[bcol + wc * 64 + nj * 16 + fr], colpart[nj]);
    }
  }
}

extern "C" void kernel_launch(void* const* d_in, const int* in_sizes, int n_in,
                              void* d_out, int out_size, void* d_ws, size_t ws_size,
                              hipStream_t stream) {
  const float* x  = (const float*)d_in[0];  // [4096,512]
  const float* W1 = (const float*)d_in[1];  // [4096,512]
  const float* b1 = (const float*)d_in[2];  // [4096]
  const float* W2 = (const float*)d_in[3];  // [4096,4096]
  const float* b2 = (const float*)d_in[4];  // [4096]
  const float* Wc = (const float*)d_in[5];  // [1,4096]
  const float* bc = (const float*)d_in[6];  // [1]
  float* out = (float*)d_out;               // [4096,1]

  char* ws = (char*)d_ws;
  unsigned short* xb  = (unsigned short*)ws; ws += (size_t)NROWS * INDIM * 2;
  unsigned short* w1b = (unsigned short*)ws; ws += (size_t)HID * INDIM * 2;
  unsigned short* w2b = (unsigned short*)ws; ws += (size_t)HID * HID * 2;
  unsigned short* h1  = (unsigned short*)ws; ws += (size_t)NROWS * HID * 2;
  unsigned short* h2  = (unsigned short*)ws; ws += (size_t)NROWS * HID * 2;
  float* norms = (float*)ws;                 ws += (size_t)NROWS * 4;

  {
    int n4 = NROWS * INDIM / 4;
    cast_f32_bf16<<<(n4 + 255) / 256, 256, 0, stream>>>(x, xb, n4);
    cast_f32_bf16<<<(n4 + 255) / 256, 256, 0, stream>>>(W1, w1b, n4);
    int m4 = HID * HID / 4;
    cast_f32_bf16<<<(m4 + 255) / 256, 256, 0, stream>>>(W2, w2b, m4);
  }

  const int grid = (NROWS / 256) * (HID / 256);  // 256

  // h1 = tanh(x @ W1^T + b1)
  gemm256<0><<<grid, 512, 0, stream>>>(xb, w1b, INDIM, HID, b1, h1, nullptr);
  // out = bc; norms = 0
  init_vecs<<<(NROWS + 255) / 256, 256, 0, stream>>>(out, norms, bc, NROWS);
  // h2 = tanh(h1 @ W2^T + b2), norms fused
  gemm256<2><<<grid, 512, 0, stream>>>(h1, w2b, HID, HID, b2, h2, norms);
  // triangular gram + classifier
  gram_tri<<<528, 256, 0, stream>>>(h2, HID, norms, Wc, out);
}

// Round 5
// 273.661 us; speedup vs baseline: 1.1028x; 1.1028x over previous
//
#include <hip/hip_runtime.h>
#include <hip/hip_bf16.h>

// FraudDetectionHybrid: h1=tanh(x@W1^T+b1); h2=tanh(h1@W2^T+b2);
// sq_ij=|h2_i|^2+|h2_j|^2-2*h2_i.h2_j; out=exp(-g*sq)@Wc^T+bc
// GEMM1/2: MX-fp8 (e4m3, unit block-scales, data pre-scaled by 2^k)
// via mfma_scale_f32_32x32x64_f8f6f4, BK=128, 4-phase asm-barrier loop.
// Gram: bf16 triangular 128^2 (verified R3 kernel).

#define NROWS 4096
#define HID   4096
#define INDIM 512
#define GAMMA_F 5e-4f

typedef float f32x4  __attribute__((ext_vector_type(4)));
typedef float f32x16 __attribute__((ext_vector_type(16)));
typedef short bf16x8 __attribute__((ext_vector_type(8)));
typedef int   i32x4  __attribute__((ext_vector_type(4)));
typedef int   i32x8  __attribute__((ext_vector_type(8)));

#define BAR() asm volatile("s_barrier" ::: "memory")
#define SCALE1 0x7F7F7F7F   // e8m0 = 127 -> 2^0 in all bytes; opsel-independent

__device__ __forceinline__ unsigned short f2bf_rne(float f) {
  union { float f; unsigned int u; } v; v.f = f;
  unsigned int r = v.u + 0x7FFFu + ((v.u >> 16) & 1u);
  return (unsigned short)(r >> 16);
}
__device__ __forceinline__ float bf2f(unsigned short u) {
  union { unsigned int u; float f; } v; v.u = ((unsigned int)u) << 16; return v.f;
}

// f32 -> OCP e4m3fn, RNE, saturate to 448, subnormals handled
__device__ __forceinline__ unsigned char f2e4m3(float x) {
  unsigned int u = __float_as_uint(x);
  unsigned char s = (unsigned char)((u >> 24) & 0x80u);
  float a = fabsf(x);
  if (a >= 448.f) return s | 0x7E;
  if (a < 0.015625f) {                      // below 2^-6: subnormal (2^-9 ulp)
    int q = (int)rintf(a * 512.f);          // 0..8 (8 == 2^-6 encodes as 0x08)
    return s | (unsigned char)q;
  }
  unsigned int ua = u & 0x7fffffffu;
  ua += 0x7FFFFu + ((ua >> 20) & 1u);       // RNE at mantissa bit 20
  int e = (int)(ua >> 23) - 127;            // -6..8
  unsigned int m = (ua >> 20) & 7u;
  return s | (unsigned char)(((e + 7) << 3) | m);
}

__global__ void cast_f32_fp8(const float* __restrict__ src,
                             unsigned char* __restrict__ dst,
                             float scale, int n8) {
  int i = blockIdx.x * blockDim.x + threadIdx.x;
  if (i >= n8) return;
  const float4* s = (const float4*)src;
  float4 v0 = s[i * 2], v1 = s[i * 2 + 1];
  unsigned int r0 = (unsigned int)f2e4m3(v0.x * scale)
                  | ((unsigned int)f2e4m3(v0.y * scale) << 8)
                  | ((unsigned int)f2e4m3(v0.z * scale) << 16)
                  | ((unsigned int)f2e4m3(v0.w * scale) << 24);
  unsigned int r1 = (unsigned int)f2e4m3(v1.x * scale)
                  | ((unsigned int)f2e4m3(v1.y * scale) << 8)
                  | ((unsigned int)f2e4m3(v1.z * scale) << 16)
                  | ((unsigned int)f2e4m3(v1.w * scale) << 24);
  uint2 o; o.x = r0; o.y = r1;
  ((uint2*)dst)[i] = o;
}

__global__ void init_vecs(float* __restrict__ out, float* __restrict__ norms,
                          const float* __restrict__ bc, int n) {
  int i = blockIdx.x * blockDim.x + threadIdx.x;
  if (i < n) { out[i] = bc[0]; norms[i] = 0.f; }
}

__device__ __forceinline__ void gload16(const void* g, void* l) {
  __builtin_amdgcn_global_load_lds(
      (const __attribute__((address_space(1))) void*)g,
      (__attribute__((address_space(3))) void*)l, 16, 0, 0);
}

// ---------------------------------------------------------------------------
// fp8 NT GEMM: D = A[M,K]*B[N,K]^T (A,B e4m3 bytes). BM=BN=256, BK=128 B,
// 8 waves (2Mx4N), per-wave 128x64 = 4mi x 2nj fragments of 32x32, K-step 64.
// LDS: 2 dbuf x 256x128 B per matrix = 128 KiB. Swizzle: 16B chunk c of row r
// stored at position c ^ (r&7) (involution; pre-swizzled global source,
// linear LDS dest; reads apply same XOR) -> uniform bank spread.
// 4 quadrant-phases/K-tile, asm barriers, one vmcnt(8)/tile (round-4 scheme).
// MFMA: mfma_scale_f32_32x32x64_f8f6f4 with unit scales (0x7F bytes).
// EPI 0: Hout(fp8) = e4m3(8*tanh(acc/512 + bias));
// EPI 2: Hout(bf16) = bf16(tanh(acc/1024 + bias)) + fused row-norm atomics.
// ---------------------------------------------------------------------------
template <int EPI>
__global__ __launch_bounds__(512, 2)
void gemm256_fp8(const unsigned char* __restrict__ A, const unsigned char* __restrict__ B,
                 int K, int N,
                 const float* __restrict__ bias, void* __restrict__ Hout_,
                 float* __restrict__ norms_out) {
  __shared__ __align__(16) unsigned char As[2][256 * 128];
  __shared__ __align__(16) unsigned char Bs[2][256 * 128];

  const int tid  = threadIdx.x;
  const int lane = tid & 63;
  const int wave = tid >> 6;
  const int wr = wave >> 2, wc = wave & 3;   // 2x4 wave grid, 128x64 out each
  const int l31 = lane & 31, lh = lane >> 5;

  const int nwg = gridDim.x;
  const int cpx = nwg >> 3;
  const int bid = blockIdx.x;
  const int swz = (bid & 7) * cpx + (bid >> 3);
  const int nbx = N >> 8;
  const int brow = (swz / nbx) << 8;
  const int bcol = (swz % nbx) << 8;

  // staging map: 4 rounds x 512 thr x 16B = 32 KiB tile per matrix
  const unsigned char* ap[4]; const unsigned char* bp[4]; int ldq[4];
  #pragma unroll
  for (int q = 0; q < 4; ++q) {
    int idx = q * 512 + tid;
    int row = idx >> 3, c = idx & 7;
    int scol = (c ^ (row & 7)) << 4;          // pre-swizzled global byte col
    ap[q] = A + (size_t)(brow + row) * K + scol;
    bp[q] = B + (size_t)(bcol + row) * K + scol;
    ldq[q] = (q * 512 + wave * 64) * 16;      // wave-uniform LDS base
  }
#define STAGE_A(p, tt) do { int kk = (tt) * 128;            \
    gload16(ap[0] + kk, &As[p][ldq[0]]);                    \
    gload16(ap[1] + kk, &As[p][ldq[1]]);                    \
    gload16(ap[2] + kk, &As[p][ldq[2]]);                    \
    gload16(ap[3] + kk, &As[p][ldq[3]]); } while (0)
#define STAGE_B(p, tt) do { int kk = (tt) * 128;            \
    gload16(bp[0] + kk, &Bs[p][ldq[0]]);                    \
    gload16(bp[1] + kk, &Bs[p][ldq[1]]);                    \
    gload16(bp[2] + kk, &Bs[p][ldq[2]]);                    \
    gload16(bp[3] + kk, &Bs[p][ldq[3]]); } while (0)

  // fragment offsets: lane reads 32 K-bytes at row, k = ks*64 + lh*32
  // byte off = row*128 + ((cp ^ (row&7))<<4), second read at off^16 (cp even)
  int aoff[4][2], boff[2][2];
#pragma unroll
  for (int mi = 0; mi < 4; ++mi) {
    int row = wr * 128 + mi * 32 + l31;
#pragma unroll
    for (int ks = 0; ks < 2; ++ks) {
      int cp = ks * 4 + (lh << 1);
      aoff[mi][ks] = row * 128 + ((cp ^ (row & 7)) << 4);
    }
  }
#pragma unroll
  for (int nj = 0; nj < 2; ++nj) {
    int row = wc * 64 + nj * 32 + l31;
#pragma unroll
    for (int ks = 0; ks < 2; ++ks) {
      int cp = ks * 4 + (lh << 1);
      boff[nj][ks] = row * 128 + ((cp ^ (row & 7)) << 4);
    }
  }

#define LDFRAG(dst, buf, off) do {                                  \
    i32x4 lo_ = *(const i32x4*)&(buf)[(off)];                       \
    i32x4 hi_ = *(const i32x4*)&(buf)[(off) ^ 16];                  \
    dst[0]=lo_[0]; dst[1]=lo_[1]; dst[2]=lo_[2]; dst[3]=lo_[3];     \
    dst[4]=hi_[0]; dst[5]=hi_[1]; dst[6]=hi_[2]; dst[7]=hi_[3]; } while (0)

#define MFMA8(d, a, b) \
    d = __builtin_amdgcn_mfma_scale_f32_32x32x64_f8f6f4( \
        a, b, d, 0, 0, 0, SCALE1, 0, SCALE1)

  const int NT = K >> 7;   // K-tiles of 128 bytes

  // prologue: tiles 0,1 fully staged (16 loads/thread)
  STAGE_A(0, 0); STAGE_B(0, 0);
  STAGE_A(1, 1); STAGE_B(1, 1);
  asm volatile("s_waitcnt vmcnt(8)" ::: "memory");   // tile0's 8 landed
  BAR();

  f32x16 acc[4][2] = {};
  i32x8 afr[2][2], bf0[2], bf1[2];

  for (int t = 0; t < NT; ++t) {
    const int p = t & 1;
    int t2 = t + 2; if (t2 >= NT) t2 -= NT;   // wrapped dummy keeps counts uniform

    // ---- ph1: A mi0-1 (8 reads) + B nj0 (4 reads) | MFMA (mi01,nj0) ----
#pragma unroll
    for (int mi = 0; mi < 2; ++mi)
#pragma unroll
      for (int ks = 0; ks < 2; ++ks) LDFRAG(afr[mi][ks], As[p], aoff[mi][ks]);
#pragma unroll
    for (int ks = 0; ks < 2; ++ks) LDFRAG(bf0[ks], Bs[p], boff[0][ks]);
    BAR();
    asm volatile("s_waitcnt lgkmcnt(0)" ::: "memory");
    __builtin_amdgcn_sched_barrier(0);
    __builtin_amdgcn_s_setprio(1);
#pragma unroll
    for (int ks = 0; ks < 2; ++ks)
#pragma unroll
      for (int mi = 0; mi < 2; ++mi) MFMA8(acc[mi][0], afr[mi][ks], bf0[ks]);
    __builtin_amdgcn_s_setprio(0);
    BAR();

    // ---- ph2: B nj1 (4 reads) | MFMA (mi01,nj1) ----
#pragma unroll
    for (int ks = 0; ks < 2; ++ks) LDFRAG(bf1[ks], Bs[p], boff[1][ks]);
    BAR();
    asm volatile("s_waitcnt lgkmcnt(0)" ::: "memory");
    __builtin_amdgcn_sched_barrier(0);
    __builtin_amdgcn_s_setprio(1);
#pragma unroll
    for (int ks = 0; ks < 2; ++ks)
#pragma unroll
      for (int mi = 0; mi < 2; ++mi) MFMA8(acc[mi][1], afr[mi][ks], bf1[ks]);
    __builtin_amdgcn_s_setprio(0);
    asm volatile("s_waitcnt lgkmcnt(0)" ::: "memory");  // B-reads done -> may overwrite Bs[p]
    BAR();

    // ---- ph3: A mi2-3 (8 reads, reuse afr); stage B(t+2) | MFMA (mi23,nj0) ----
#pragma unroll
    for (int mi = 0; mi < 2; ++mi)
#pragma unroll
      for (int ks = 0; ks < 2; ++ks) LDFRAG(afr[mi][ks], As[p], aoff[2 + mi][ks]);
    STAGE_B(p, t2);
    BAR();
    asm volatile("s_waitcnt lgkmcnt(0)" ::: "memory");
    __builtin_amdgcn_sched_barrier(0);
    __builtin_amdgcn_s_setprio(1);
#pragma unroll
    for (int ks = 0; ks < 2; ++ks)
#pragma unroll
      for (int mi = 0; mi < 2; ++mi) MFMA8(acc[2 + mi][0], afr[mi][ks], bf0[ks]);
    __builtin_amdgcn_s_setprio(0);
    asm volatile("s_waitcnt lgkmcnt(0)" ::: "memory");  // A-reads done -> may overwrite As[p]
    BAR();

    // ---- ph4: stage A(t+2) | MFMA (mi23,nj1) | vmcnt(8) ----
    STAGE_A(p, t2);
    __builtin_amdgcn_s_setprio(1);
#pragma unroll
    for (int ks = 0; ks < 2; ++ks)
#pragma unroll
      for (int mi = 0; mi < 2; ++mi) MFMA8(acc[2 + mi][1], afr[mi][ks], bf1[ks]);
    __builtin_amdgcn_s_setprio(0);
    asm volatile("s_waitcnt vmcnt(8)" ::: "memory");    // t+1's tile landed
    BAR();
  }
  asm volatile("s_waitcnt vmcnt(0)" ::: "memory");

  // C/D layout (32x32, shape-determined, m74/m101): col = lane&31,
  // row = (reg&3) + 8*(reg>>2) + 4*(lane>>5)
  const float rescale = (EPI == 0) ? (1.f / 512.f) : (1.f / 1024.f);
  float bv[2];
#pragma unroll
  for (int nj = 0; nj < 2; ++nj) bv[nj] = bias[bcol + wc * 64 + nj * 32 + l31];

#pragma unroll
  for (int mi = 0; mi < 4; ++mi) {
    int rbase = brow + wr * 128 + mi * 32 + 4 * lh;
#pragma unroll
    for (int g = 0; g < 4; ++g) {
#pragma unroll
      for (int h = 0; h < 4; ++h) {
        int reg = g * 4 + h;
        int row = rbase + h + 8 * g;
        float ns = 0.f;
#pragma unroll
        for (int nj = 0; nj < 2; ++nj) {
          int col = bcol + wc * 64 + nj * 32 + l31;
          float v = tanhf(acc[mi][nj][reg] * rescale + bv[nj]);
          if (EPI == 0) {
            ((unsigned char*)Hout_)[(size_t)row * N + col] = f2e4m3(8.f * v);
          } else {
            unsigned short q = f2bf_rne(v);
            ((unsigned short*)Hout_)[(size_t)row * N + col] = q;
            float vq = bf2f(q);
            ns += vq * vq;
          }
        }
        if (EPI == 2) {
          ns += __shfl_xor(ns, 1);
          ns += __shfl_xor(ns, 2);
          ns += __shfl_xor(ns, 4);
          ns += __shfl_xor(ns, 8);
          ns += __shfl_xor(ns, 16);
          if (l31 == 0) atomicAdd(&norms_out[row], ns);
        }
      }
    }
  }
#undef STAGE_A
#undef STAGE_B
#undef LDFRAG
#undef MFMA8
}

// ---------------------------------------------------------------------------
// Triangular gram, bf16 (verified round-3 kernel): 128x128 tiles over the
// lower triangle (528 blocks); each exp feeds out[row] AND out[col].
// ---------------------------------------------------------------------------
__global__ __launch_bounds__(256, 2)
void gram_tri(const unsigned short* __restrict__ H, int K,
              const float* __restrict__ norms, const float* __restrict__ Wc,
              float* __restrict__ out) {
  __shared__ __align__(16) unsigned short As[128 * 32];
  __shared__ __align__(16) unsigned short Bs[128 * 32];

  const int tid  = threadIdx.x;
  const int lane = tid & 63;
  const int wave = tid >> 6;
  const int wr = wave >> 1, wc = wave & 1;
  const int fr = lane & 15, fq = lane >> 4;

  const int bid = blockIdx.x;
  const int swz = (bid & 7) * 66 + (bid >> 3);
  int I = (int)((sqrtf(8.0f * (float)swz + 1.0f) - 1.0f) * 0.5f);
  while ((I + 1) * (I + 2) / 2 <= swz) ++I;
  while (I * (I + 1) / 2 > swz) --I;
  const int J = swz - I * (I + 1) / 2;
  const int brow = I << 7, bcol = J << 7;
  const bool diag = (I == J);

  f32x4 acc[4][4] = {};

  for (int k0 = 0; k0 < K; k0 += 32) {
    __syncthreads();
#pragma unroll
    for (int q = 0; q < 2; ++q) {
      int idx = q * 256 + tid;
      int row = idx >> 2, c = idx & 3;
      int col = (c ^ ((row >> 1) & 3)) << 3;
      gload16(H + (size_t)(brow + row) * K + k0 + col, &As[(q * 256 + wave * 64) * 8]);
      gload16(H + (size_t)(bcol + row) * K + k0 + col, &Bs[(q * 256 + wave * 64) * 8]);
    }
    __syncthreads();

    bf16x8 af[4], bfrag[4];
#pragma unroll
    for (int mi = 0; mi < 4; ++mi) {
      int row = wr * 64 + mi * 16 + fr;
      af[mi] = *(const bf16x8*)&As[row * 32 + ((fq ^ ((row >> 1) & 3)) << 3)];
    }
#pragma unroll
    for (int nj = 0; nj < 4; ++nj) {
      int row = wc * 64 + nj * 16 + fr;
      bfrag[nj] = *(const bf16x8*)&Bs[row * 32 + ((fq ^ ((row >> 1) & 3)) << 3)];
    }
#pragma unroll
    for (int mi = 0; mi < 4; ++mi)
#pragma unroll
      for (int nj = 0; nj < 4; ++nj)
        acc[mi][nj] = __builtin_amdgcn_mfma_f32_16x16x32_bf16(af[mi], bfrag[nj], acc[mi][nj], 0, 0, 0);
  }

  float ncol[4], wcv[4];
#pragma unroll
  for (int nj = 0; nj < 4; ++nj) {
    int col = bcol + wc * 64 + nj * 16 + fr;
    ncol[nj] = norms[col];
    wcv[nj]  = Wc[col];
  }
  float colpart[4] = {0.f, 0.f, 0.f, 0.f};
#pragma unroll
  for (int mi = 0; mi < 4; ++mi) {
    int row0 = brow + wr * 64 + mi * 16 + fq * 4;
    float4 nr4  = *(const float4*)&norms[row0];
    float4 wcr4 = *(const float4*)&Wc[row0];
#pragma unroll
    for (int rr = 0; rr < 4; ++rr) {
      float nrow = (rr == 0) ? nr4.x : (rr == 1) ? nr4.y : (rr == 2) ? nr4.z : nr4.w;
      float wrow = (rr == 0) ? wcr4.x : (rr == 1) ? wcr4.y : (rr == 2) ? wcr4.z : wcr4.w;
      float rowpart = 0.f;
#pragma unroll
      for (int nj = 0; nj < 4; ++nj) {
        float sq = nrow + ncol[nj] - 2.0f * acc[mi][nj][rr];
        float e = __expf(-GAMMA_F * sq);
        rowpart += e * wcv[nj];
        colpart[nj] += e * wrow;
      }
      rowpart += __shfl_xor(rowpart, 1);
      rowpart += __shfl_xor(rowpart, 2);
      rowpart += __shfl_xor(rowpart, 4);
      rowpart += __shfl_xor(rowpart, 8);
      if (fr == 0) atomicAdd(&out[row0 + rr], rowpart);
    }
  }
  if (!diag) {
#pragma unroll
    for (int nj = 0; nj < 4; ++nj) {
      colpart[nj] += __shfl_xor(colpart[nj], 16);
      colpart[nj] += __shfl_xor(colpart[nj], 32);
      if (fq == 0) atomicAdd(&out[bcol + wc * 64 + nj * 16 + fr], colpart[nj]);
    }
  }
}

extern "C" void kernel_launch(void* const* d_in, const int* in_sizes, int n_in,
                              void* d_out, int out_size, void* d_ws, size_t ws_size,
                              hipStream_t stream) {
  const float* x  = (const float*)d_in[0];  // [4096,512]
  const float* W1 = (const float*)d_in[1];  // [4096,512]
  const float* b1 = (const float*)d_in[2];  // [4096]
  const float* W2 = (const float*)d_in[3];  // [4096,4096]
  const float* b2 = (const float*)d_in[4];  // [4096]
  const float* Wc = (const float*)d_in[5];  // [1,4096]
  const float* bc = (const float*)d_in[6];  // [1]
  float* out = (float*)d_out;               // [4096,1]

  char* ws = (char*)d_ws;
  unsigned char* xq  = (unsigned char*)ws; ws += (size_t)NROWS * INDIM;   // x*16   fp8
  unsigned char* w1q = (unsigned char*)ws; ws += (size_t)HID * INDIM;     // W1*32  fp8
  unsigned char* w2q = (unsigned char*)ws; ws += (size_t)HID * HID;       // W2*128 fp8
  unsigned char* h1q = (unsigned char*)ws; ws += (size_t)NROWS * HID;     // h1*8   fp8
  unsigned short* h2 = (unsigned short*)ws; ws += (size_t)NROWS * HID * 2; // h2 bf16
  float* norms = (float*)ws;                ws += (size_t)NROWS * 4;

  {
    int n8 = NROWS * INDIM / 8;
    cast_f32_fp8<<<(n8 + 255) / 256, 256, 0, stream>>>(x, xq, 16.f, n8);
    cast_f32_fp8<<<(n8 + 255) / 256, 256, 0, stream>>>(W1, w1q, 32.f, n8);
    int m8 = HID * HID / 8;
    cast_f32_fp8<<<(m8 + 255) / 256, 256, 0, stream>>>(W2, w2q, 128.f, m8);
  }

  const int grid = (NROWS / 256) * (HID / 256);  // 256

  // h1 = tanh((x16 @ W1_32^T)/512 + b1), stored as fp8(8*h1)
  gemm256_fp8<0><<<grid, 512, 0, stream>>>(xq, w1q, INDIM, HID, b1, h1q, nullptr);
  // out = bc; norms = 0
  init_vecs<<<(NROWS + 255) / 256, 256, 0, stream>>>(out, norms, bc, NROWS);
  // h2 = tanh((h1_8 @ W2_128^T)/1024 + b2) -> bf16, norms fused
  gemm256_fp8<2><<<grid, 512, 0, stream>>>(h1q, w2q, HID, HID, b2, h2, norms);
  // triangular gram + classifier (bf16)
  gram_tri<<<528, 256, 0, stream>>>(h2, HID, norms, Wc, out);
}